// Round 2
// baseline (30517.438 us; speedup 1.0000x reference)
//
#include <hip/hip_runtime.h>

// ---------------------------------------------------------------------------
// RevRNN persistent kernel, round 5: batch-intra-WG, minimal-poll exchange.
// - 16 WGs x 512 threads (8 waves = 4 row-tiles x 2 col-groups). Each WG owns
//   ALL 64 batch rows for its 16 output columns -> batch mean is an LDS
//   reduction; producer publishes PRE-CENTERED f16 state.
// - Cross-WG exchange keeps the harness-verified round-3 semantics:
//   __hip_atomic_* AGENT scope (LLC). What changed is the SHAPE:
//   flags are ONE 64B line of 16 u32 tags per parity; poll = 1 atomic
//   lane-load + __all. Kills the 8KB-scatter poll storm of round 3.
// - Producer: centered stores -> vmcnt(0) -> barrier -> tid0 tag store.
//   WAR-safe: WG j's tag t+2 on flagA implies j finished READING state1
//   (its TAIL consumed the loads before the tag), so overwriting state1 at
//   phase A(t+1) after polling flagA>=t+2 is safe (symmetric for state0).
// - Trims kept from round 4 (sync-independent): x-MFMAs + pe hoisted before
//   the poll; x(t+1) prefetch before phase-B poll; dual MFMA acc chains;
//   branch-free exp-based tanh. xa[] dropped (re-convert xf in phase B) to
//   fit the 256-VGPR cap of 512-thread WGs (2 waves/SIMD).
// - Sticky 'alive' spin guard -> loud wrong answer instead of hang.
// ---------------------------------------------------------------------------

#define T_TOT 2056
#define S_SEQ 2048

typedef _Float16 f16x8 __attribute__((ext_vector_type(8)));
typedef float f32x4 __attribute__((ext_vector_type(4)));

// poll one 64B tag line: lane ln polls tag[ln&15]; exit when all 16 >= TAG.
#define POLL(FL, TAG)                                                          \
  {                                                                            \
    const unsigned tg_ = (unsigned)(TAG);                                      \
    int it_ = 0;                                                               \
    for (;;) {                                                                 \
      const unsigned tv_ = __hip_atomic_load(                                  \
          (FL) + (ln & 15), __ATOMIC_RELAXED, __HIP_MEMORY_SCOPE_AGENT);       \
      if (__all((int)(tv_ >= tg_))) break;                                     \
      if (!alive || ++it_ > (1 << 17)) { alive = 0; break; }                   \
    }                                                                          \
  }

// consume pre-centered state + gate + mean-center + publish + tag.
#define TAIL(WS, SIN, SOUT, FOUT, RAW, TAGOUT, PAR)                            \
  {                                                                            \
    const unsigned long long* sp_ =                                            \
        (const unsigned long long*)(const void*)(SIN) + (size_t)arow * 64 +    \
        kq * 2;                                                                \
    _Pragma("unroll")                                                          \
    for (int kk = 0; kk < 8; ++kk) {                                           \
      union { unsigned long long q[2]; f16x8 v; } sv_;                         \
      sv_.q[0] = __hip_atomic_load(sp_ + kk * 8 + 0, __ATOMIC_RELAXED,         \
                                   __HIP_MEMORY_SCOPE_AGENT);                  \
      sv_.q[1] = __hip_atomic_load(sp_ + kk * 8 + 1, __ATOMIC_RELAXED,         \
                                   __HIP_MEMORY_SCOPE_AGENT);                  \
      if (kk & 1)                                                              \
        acc1 = __builtin_amdgcn_mfma_f32_16x16x32_f16(sv_.v, (WS)[kk], acc1,   \
                                                      0, 0, 0);                \
      else                                                                     \
        acc0 = __builtin_amdgcn_mfma_f32_16x16x32_f16(sv_.v, (WS)[kk], acc0,   \
                                                      0, 0, 0);                \
    }                                                                          \
    float nv_[4], ssum_ = 0.f;                                                 \
    _Pragma("unroll")                                                          \
    for (int r = 0; r < 4; ++r) {                                              \
      const float z = acc0[r] + acc1[r];                                       \
      const float p = __shfl_xor(z, 8);                                        \
      const float z0 = (n < 8) ? z : p;                                        \
      const float z1 = (n < 8) ? p : z;                                        \
      /* branch-free tanh: clamp +-10, (e-1)/(e+1); err << f16 quantization */ \
      const float z1c = fminf(fmaxf(z1, -10.f), 10.f);                         \
      const float e2 = __expf(2.f * z1c);                                      \
      const float th = (e2 - 1.f) * __builtin_amdgcn_rcpf(e2 + 1.f);           \
      const float cv = fminf(fmaxf(z0, 0.f), 6.f) * th;                        \
      const float o = ((RAW)[r] + cv) * 0.5f;                                  \
      (RAW)[r] = o; nv_[r] = o; ssum_ += o;                                    \
    }                                                                          \
    /* 16-row column sum within wave, then 64-row mean across rt via LDS */    \
    ssum_ += __shfl_xor(ssum_, 16);                                            \
    ssum_ += __shfl_xor(ssum_, 32);                                            \
    red[PAR][rt][cg][ln] = ssum_;                                              \
    __syncthreads();                                                           \
    const float mean_ =                                                        \
        (red[PAR][0][cg][ln] + red[PAR][1][cg][ln] + red[PAR][2][cg][ln] +     \
         red[PAR][3][cg][ln]) * 0.015625f;                                     \
    unsigned dv_[4];                                                           \
    _Pragma("unroll")                                                          \
    for (int r = 0; r < 4; ++r) {                                              \
      union { _Float16 h; unsigned short u; } hb_;                             \
      hb_.h = (_Float16)(nv_[r] - mean_);                                      \
      const unsigned pr_ = (unsigned)__shfl_xor((int)hb_.u, 1) & 0xFFFFu;      \
      dv_[r] = (unsigned)hb_.u | (pr_ << 16);                                  \
    }                                                                          \
    if ((n & 1) == 0 && n < 8) {                                               \
      _Pragma("unroll")                                                        \
      for (int r = 0; r < 4; ++r)                                              \
        __hip_atomic_store((SOUT) + (size_t)(16 * rt + kq * 4 + r) * 128 +     \
                               (ocol >> 1),                                    \
                           dv_[r], __ATOMIC_RELAXED, __HIP_MEMORY_SCOPE_AGENT);\
    }                                                                          \
    asm volatile("s_waitcnt vmcnt(0)" ::: "memory");                           \
    __syncthreads(); /* all 8 waves' stores acked before the WG tag */         \
    if (tid == 0)                                                              \
      __hip_atomic_store((FOUT) + wg, (unsigned)(TAGOUT), __ATOMIC_RELAXED,    \
                         __HIP_MEMORY_SCOPE_AGENT);                            \
  }

__launch_bounds__(512, 2)
__global__ void rnn_kernel(const float* __restrict__ xg,
                           const float* __restrict__ hs,
                           const float* __restrict__ W0,
                           const float* __restrict__ W1,
                           float* __restrict__ out,
                           unsigned* __restrict__ flagA,
                           unsigned* __restrict__ flagB,
                           unsigned* __restrict__ state0,
                           unsigned* __restrict__ state1) {
  const int wg  = (int)blockIdx.x;   // 0..15: owns ocols 16*wg..16*wg+15
  const int tid = (int)threadIdx.x;  // 0..511
  const int w   = tid >> 6;          // wave 0..7
  const int rt  = w >> 1;            // batch row-tile 0..3 (rows 16rt..)
  const int cg  = w & 1;             // col-group 0..1
  const int ln  = tid & 63;
  const int n   = ln & 15;           // A-row / packed col within tile
  const int kq  = ln >> 4;           // quad 0..3
  const int ocol = wg * 16 + cg * 8 + (n & 7);     // owned output column
  const int wrow = (n < 8) ? ocol : (256 + ocol);  // packed W row (z0|z1)
  const int arow = 16 * rt + n;                    // A-fragment batch row

  __shared__ float red[2][4][2][64];  // [parity][rt][cg][lane] 4KB

  // ---- preload W fragments (state part + x part) into registers ----
  f16x8 w0s[8], w0x[8], w1s[8], w1x[8];
  float w0pa, w0pb, w1pa, w1pb;
  {
    const float* r0 = W0 + (size_t)wrow * 514;
    const float* r1 = W1 + (size_t)wrow * 514;
#pragma unroll
    for (int kk = 0; kk < 8; ++kk) {
      const int k0 = kk * 32 + kq * 8;
      f16x8 a, bx, a1, bx1;
#pragma unroll
      for (int j = 0; j < 8; ++j) {
        a[j]   = (_Float16)r0[k0 + j];
        bx[j]  = (_Float16)r0[256 + k0 + j];
        a1[j]  = (_Float16)r1[k0 + j];
        bx1[j] = (_Float16)r1[256 + k0 + j];
      }
      w0s[kk] = a; w0x[kk] = bx; w1s[kk] = a1; w1x[kk] = bx1;
    }
    w0pa = r0[512]; w0pb = r0[513];
    w1pa = r1[512]; w1pb = r1[513];
  }

  // ---- raw recurrence state (fp32, register-resident) ----
  float raw0[4], raw1[4];
#pragma unroll
  for (int r = 0; r < 4; ++r) { raw0[r] = hs[ocol]; raw1[r] = hs[256 + ocol]; }

  int alive = 1;

  // ---- init: state0 is all-zero via memset (centered broadcast h0 == 0),
  //      so the init publish is just the version-1 tag.
  if (tid == 0)
    __hip_atomic_store(flagA + wg, 1u, __ATOMIC_RELAXED,
                       __HIP_MEMORY_SCOPE_AGENT);

  // ---- x prefetch for t=0 ----
  f32x4 xf[16];
  {
    const float* xp = xg + (size_t)arow * S_SEQ * 256 + kq * 8;
#pragma unroll
    for (int kk = 0; kk < 8; ++kk) {
      xf[2 * kk]     = *(const f32x4*)(xp + kk * 32);
      xf[2 * kk + 1] = *(const f32x4*)(xp + kk * 32 + 4);
    }
  }

  for (int t = 0; t < T_TOT; ++t) {
    const float pe0 = (float)(t + 1);
    const float pe1 = (pe0 - 1028.5f) * (1.0f / 1028.5f);
    const int have_x = (t < S_SEQ);

    // ---------------- phase A: o1 = (h1 + calc(h0c, s, W0)) * 0.5 ----------
    {
      f32x4 acc0, acc1;
      const float pt = pe0 * w0pa + pe1 * w0pb;
      acc0[0] = pt; acc0[1] = pt; acc0[2] = pt; acc0[3] = pt;
      acc1[0] = 0.f; acc1[1] = 0.f; acc1[2] = 0.f; acc1[3] = 0.f;
      // x part BEFORE the poll: overlaps the spin, off the critical path.
      if (have_x) {
#pragma unroll
        for (int kk = 0; kk < 8; ++kk) {
          f16x8 af;
#pragma unroll
          for (int j = 0; j < 4; ++j) {
            af[j]     = (_Float16)xf[2 * kk][j];
            af[4 + j] = (_Float16)xf[2 * kk + 1][j];
          }
          if (kk & 1)
            acc1 = __builtin_amdgcn_mfma_f32_16x16x32_f16(af, w0x[kk], acc1,
                                                          0, 0, 0);
          else
            acc0 = __builtin_amdgcn_mfma_f32_16x16x32_f16(af, w0x[kk], acc0,
                                                          0, 0, 0);
        }
      }
      POLL(flagA, t + 1);
      TAIL(w0s, state0, state1, flagB, raw1, t + 1, 0);
    }

    // ---------------- phase B: o0 = (h0 + calc(o1c, s, W1)) * 0.5 ----------
    {
      f32x4 acc0, acc1;
      const float pt = pe0 * w1pa + pe1 * w1pb;
      acc0[0] = pt; acc0[1] = pt; acc0[2] = pt; acc0[3] = pt;
      acc1[0] = 0.f; acc1[1] = 0.f; acc1[2] = 0.f; acc1[3] = 0.f;
      if (have_x) {
#pragma unroll
        for (int kk = 0; kk < 8; ++kk) {  // re-convert xf (keeps VGPRs low)
          f16x8 af;
#pragma unroll
          for (int j = 0; j < 4; ++j) {
            af[j]     = (_Float16)xf[2 * kk][j];
            af[4 + j] = (_Float16)xf[2 * kk + 1][j];
          }
          if (kk & 1)
            acc1 = __builtin_amdgcn_mfma_f32_16x16x32_f16(af, w1x[kk], acc1,
                                                          0, 0, 0);
          else
            acc0 = __builtin_amdgcn_mfma_f32_16x16x32_f16(af, w1x[kk], acc0,
                                                          0, 0, 0);
        }
      }
      // prefetch x(t+1) now: in flight across poll B + TAIL B.
      if (t + 1 < S_SEQ) {
        const float* xp = xg + ((size_t)arow * S_SEQ + (t + 1)) * 256 + kq * 8;
#pragma unroll
        for (int kk = 0; kk < 8; ++kk) {
          xf[2 * kk]     = *(const f32x4*)(xp + kk * 32);
          xf[2 * kk + 1] = *(const f32x4*)(xp + kk * 32 + 4);
        }
      }
      POLL(flagB, t + 1);
      TAIL(w1s, state1, state0, flagA, raw0, t + 2, 1);
    }
  }

  // ---- final h = [o0 | o1] fp32 ----
  if (n < 8) {
#pragma unroll
    for (int r = 0; r < 4; ++r) {
      const int row = 16 * rt + kq * 4 + r;
      out[(size_t)row * 512 + ocol] = raw0[r];
      out[(size_t)row * 512 + 256 + ocol] = raw1[r];
    }
  }
}

#undef TAIL
#undef POLL

extern "C" void kernel_launch(void* const* d_in, const int* in_sizes, int n_in,
                              void* d_out, int out_size, void* d_ws, size_t ws_size,
                              hipStream_t stream) {
  (void)in_sizes; (void)n_in; (void)out_size; (void)ws_size;
  const float* x  = (const float*)d_in[0];
  const float* hs = (const float*)d_in[1];
  const float* W0 = (const float*)d_in[2];
  const float* W1 = (const float*)d_in[3];
  float* out = (float*)d_out;

  char* ws = (char*)d_ws;
  unsigned* state0 = (unsigned*)ws;                  // 32 KB (zeroed)
  unsigned* state1 = (unsigned*)(ws + 32768);        // 32 KB (no init needed)
  unsigned* flagA  = (unsigned*)(ws + 65536);        // 64 B line
  unsigned* flagB  = (unsigned*)(ws + 65536 + 64);   // 64 B line

  // state0 must be zero (centered broadcast h0 == 0); flags must start 0
  // (0xAA poison would read as a huge valid tag).
  hipMemsetAsync(ws, 0, 32768, stream);
  hipMemsetAsync(ws + 65536, 0, 128, stream);
  rnn_kernel<<<dim3(16), dim3(512), 0, stream>>>(x, hs, W0, W1, out,
                                                 flagA, flagB, state0, state1);
}

// Round 4
// 14755.658 us; speedup vs baseline: 2.0682x; 2.0682x over previous
//
#include <hip/hip_runtime.h>

// ---------------------------------------------------------------------------
// RevRNN persistent kernel, round 7 = round 6 protocol, workspace-independent.
// Round 6 never executed ("container failed twice") - prime suspect is the
// 144KB d_ws footprint (rounds 3/4 only proved ~82KB safe). Fix: exchange
// arrays live in __device__ globals, zeroed by a prologue init kernel on the
// same stream (graph-capture safe, replayed per iteration). d_ws unused.
//
// Protocol (unchanged from round 6, audited):
// - 32 WGs x 256 thr; 4 batch-groups x 8 col-groups; W register-resident;
//   consumer-side centering; agent-scope atomics (harness-verified path).
// - State cells u64 {phase_tag:32 | 2xf16:32}: self-validating. Producer
//   publish is fire-and-forget (no vmcnt ack, no separate flag).
// - Consumer merges poll+load: one loop spins on 4 partial u64 + 8 state u64
//   (per-wave disjoint K-slice); payloads already in registers on exit ->
//   LDS; mean barrier doubles as state-distribution barrier.
// - WAR-safe: pa fan-in covers all 32 WGs; publishes sit after the intra-WG
//   barrier, so a WG's tag-p output implies it fully consumed tag-(p-1).
// - Trims: x-MFMAs before the poll, x(t+1) prefetch in phase B, dual MFMA
//   accumulator chains, branch-free exp-based tanh.
// - Sticky 'alive' guard -> loud wrong answer instead of hang.
// ---------------------------------------------------------------------------

#define T_TOT 2056
#define S_SEQ 2048

typedef _Float16 f16x8 __attribute__((ext_vector_type(8)));
typedef float f32x4 __attribute__((ext_vector_type(4)));

// exchange arrays: static device globals (no workspace-size dependency)
__device__ unsigned long long g_st0[8192];  // [64 rows][128 colpair cells]
__device__ unsigned long long g_st1[8192];
__device__ unsigned long long g_pa0[1024];  // [256 ocol][4 b-groups]
__device__ unsigned long long g_pa1[1024];

__global__ void init_ws() {
  const int i = (int)blockIdx.x * 256 + (int)threadIdx.x;  // 8192 threads
  g_st0[i] = 0ull;
  g_st1[i] = 0ull;
  if (i < 1024) { g_pa0[i] = 0ull; g_pa1[i] = 0ull; }
}

#define AL(P) __hip_atomic_load((P), __ATOMIC_RELAXED, __HIP_MEMORY_SCOPE_AGENT)
#define AS(P, V)                                                               \
  __hip_atomic_store((P), (V), __ATOMIC_RELAXED, __HIP_MEMORY_SCOPE_AGENT)

// One phase: merged poll(partials+state slice) -> LDS -> barrier -> centered
// MFMA -> gate -> tagged publish (fire-and-forget) -> end barrier.
#define PHASE(WS, SIN, PIN, TAGIN, SOUT, POUT, TAGOUT, RAW)                    \
  {                                                                            \
    const unsigned long long* pp_ = (PIN) + 4 * tid;                           \
    const unsigned long long* sp_ =                                            \
        (SIN) + (size_t)(16 * b + n) * 128 + (2 * wv) * 16 + kq * 4;           \
    unsigned long long q0_, q1_, q2_, q3_;                                     \
    unsigned long long s0_, s1_, s2_, s3_, s4_, s5_, s6_, s7_;                 \
    const unsigned tg_ = (unsigned)(TAGIN);                                    \
    int it_ = 0;                                                               \
    for (;;) {                                                                 \
      q0_ = AL(pp_ + 0); q1_ = AL(pp_ + 1);                                    \
      q2_ = AL(pp_ + 2); q3_ = AL(pp_ + 3);                                    \
      s0_ = AL(sp_ + 0); s1_ = AL(sp_ + 1);                                    \
      s2_ = AL(sp_ + 2); s3_ = AL(sp_ + 3);                                    \
      s4_ = AL(sp_ + 16); s5_ = AL(sp_ + 17);                                  \
      s6_ = AL(sp_ + 18); s7_ = AL(sp_ + 19);                                  \
      const unsigned ok_ =                                                     \
          ((unsigned)(q0_ >> 32) >= tg_) & ((unsigned)(q1_ >> 32) >= tg_) &    \
          ((unsigned)(q2_ >> 32) >= tg_) & ((unsigned)(q3_ >> 32) >= tg_) &    \
          ((unsigned)(s0_ >> 32) >= tg_) & ((unsigned)(s1_ >> 32) >= tg_) &    \
          ((unsigned)(s2_ >> 32) >= tg_) & ((unsigned)(s3_ >> 32) >= tg_) &    \
          ((unsigned)(s4_ >> 32) >= tg_) & ((unsigned)(s5_ >> 32) >= tg_) &    \
          ((unsigned)(s6_ >> 32) >= tg_) & ((unsigned)(s7_ >> 32) >= tg_);     \
      if (ok_) break;                                                          \
      if (!alive || ++it_ > (1 << 17)) { alive = 0; break; }                   \
    }                                                                          \
    const float mean_ = (__uint_as_float((unsigned)q0_) +                      \
                         __uint_as_float((unsigned)q1_) +                      \
                         __uint_as_float((unsigned)q2_) +                      \
                         __uint_as_float((unsigned)q3_)) * 0.015625f;          \
    mean_h[tid] = (_Float16)mean_;                                             \
    {                                                                          \
      unsigned long long* lp_ =                                                \
          (unsigned long long*)&lds_s[n][(2 * wv) * 16 + kq * 4];              \
      lp_[0] = ((unsigned long long)(unsigned)s1_ << 32) | (unsigned)s0_;      \
      lp_[1] = ((unsigned long long)(unsigned)s3_ << 32) | (unsigned)s2_;      \
      lp_[8] = ((unsigned long long)(unsigned)s5_ << 32) | (unsigned)s4_;      \
      lp_[9] = ((unsigned long long)(unsigned)s7_ << 32) | (unsigned)s6_;      \
    }                                                                          \
    __syncthreads();                                                           \
    _Pragma("unroll")                                                          \
    for (int kk = 0; kk < 8; ++kk) {                                           \
      const f16x8 sv_ = *(const f16x8*)&lds_s[n][kk * 16 + kq * 4];            \
      const f16x8 mv_ = *(const f16x8*)&mean_h[kk * 32 + kq * 8];              \
      if (kk & 1)                                                              \
        acc1 = __builtin_amdgcn_mfma_f32_16x16x32_f16(sv_ - mv_, (WS)[kk],     \
                                                      acc1, 0, 0, 0);          \
      else                                                                     \
        acc0 = __builtin_amdgcn_mfma_f32_16x16x32_f16(sv_ - mv_, (WS)[kk],     \
                                                      acc0, 0, 0, 0);          \
    }                                                                          \
    float nv_[4], ssum_ = 0.f;                                                 \
    _Pragma("unroll")                                                          \
    for (int r = 0; r < 4; ++r) {                                              \
      const float z = acc0[r] + acc1[r];                                       \
      const float p = __shfl_xor(z, 8);                                        \
      const float z0 = (n < 8) ? z : p;                                        \
      const float z1 = (n < 8) ? p : z;                                        \
      /* branch-free tanh: clamp +-10, (e-1)/(e+1); err << f16 quantization */ \
      const float z1c = fminf(fmaxf(z1, -10.f), 10.f);                         \
      const float e2 = __expf(2.f * z1c);                                      \
      const float th = (e2 - 1.f) * __builtin_amdgcn_rcpf(e2 + 1.f);           \
      const float cv = fminf(fmaxf(z0, 0.f), 6.f) * th;                        \
      const float o = ((RAW)[r] + cv) * 0.5f;                                  \
      (RAW)[r] = o; nv_[r] = o; ssum_ += o;                                    \
    }                                                                          \
    ssum_ += __shfl_xor(ssum_, 16);                                            \
    ssum_ += __shfl_xor(ssum_, 32);                                            \
    _Pragma("unroll")                                                          \
    for (int r = 0; r < 4; ++r) {                                              \
      union { _Float16 h; unsigned short u; } hb_;                             \
      hb_.h = (_Float16)nv_[r];                                                \
      const unsigned pr_ = (unsigned)__shfl_xor((int)hb_.u, 1) & 0xFFFFu;      \
      if ((n & 1) == 0 && n < 8) {                                             \
        const unsigned dw_ = (unsigned)hb_.u | (pr_ << 16);                    \
        AS((SOUT) + (size_t)(16 * b + kq * 4 + r) * 128 + (ocol >> 1),         \
           ((unsigned long long)(unsigned)(TAGOUT) << 32) |                    \
               (unsigned long long)dw_);                                       \
      }                                                                        \
    }                                                                          \
    if (kq == 0 && n < 8)                                                      \
      AS((POUT) + (size_t)ocol * 4 + b,                                        \
         ((unsigned long long)(unsigned)(TAGOUT) << 32) |                      \
             (unsigned long long)__float_as_uint(ssum_));                      \
    __syncthreads(); /* protect lds_s/mean_h before next phase's fill */       \
  }

__launch_bounds__(256, 1)
__global__ void rnn_kernel(const float* __restrict__ xg,
                           const float* __restrict__ hs,
                           const float* __restrict__ W0,
                           const float* __restrict__ W1,
                           float* __restrict__ out) {
  const int wgid = (int)blockIdx.x;        // 0..31
  const int b = wgid & 3;                  // batch group: rows 16b..16b+15
  const int c = wgid >> 2;                 // col group: o-cols 32c..32c+31
  const int tid = (int)threadIdx.x;
  const int wv = tid >> 6;                 // wave 0..3
  const int ln = tid & 63;
  const int n = ln & 15;                   // packed col in tile / A-row
  const int kq = ln >> 4;                  // quad 0..3
  const int ocol = c * 32 + wv * 8 + (n & 7);      // owned output column
  const int wrow = (n < 8) ? ocol : (256 + ocol);  // packed W row (z0|z1)

  __shared__ __align__(16) unsigned lds_s[16][132];   // state payload, padded
  __shared__ __align__(16) _Float16 mean_h[256];

  // ---- preload W fragments (state part + x part) into registers ----
  f16x8 w0s[8], w0x[8], w1s[8], w1x[8];
  float w0pa, w0pb, w1pa, w1pb;
  {
    const float* r0 = W0 + (size_t)wrow * 514;
    const float* r1 = W1 + (size_t)wrow * 514;
#pragma unroll
    for (int kk = 0; kk < 8; ++kk) {
      const int k0 = kk * 32 + kq * 8;
      f16x8 a, bx, a1, bx1;
#pragma unroll
      for (int j = 0; j < 8; ++j) {
        a[j]   = (_Float16)r0[k0 + j];
        bx[j]  = (_Float16)r0[256 + k0 + j];
        a1[j]  = (_Float16)r1[k0 + j];
        bx1[j] = (_Float16)r1[256 + k0 + j];
      }
      w0s[kk] = a; w0x[kk] = bx; w1s[kk] = a1; w1x[kk] = bx1;
    }
    w0pa = r0[512]; w0pb = r0[513];
    w1pa = r1[512]; w1pb = r1[513];
  }

  // ---- raw recurrence state (fp32, register-resident) ----
  float raw0[4], raw1[4];
#pragma unroll
  for (int r = 0; r < 4; ++r) { raw0[r] = hs[ocol]; raw1[r] = hs[256 + ocol]; }

  int alive = 1;

  // ---- init publish: tagged uncentered h0 pairs + tagged partials, tag 1.
  //      Fire-and-forget (self-validating); consumers spin on tag 0 until
  //      these land. init_ws zeroed everything, so unwritten cells read 0.
  {
    union { _Float16 h; unsigned short u; } e0, e1;
    e0.h = (_Float16)hs[ocol]; e1.h = (_Float16)hs[ocol + 1];
    const unsigned dw = (unsigned)e0.u | ((unsigned)e1.u << 16);
    if ((n & 1) == 0 && n < 8) {
#pragma unroll
      for (int r = 0; r < 4; ++r)
        AS(g_st0 + (size_t)(16 * b + kq * 4 + r) * 128 + (ocol >> 1),
           (1ull << 32) | (unsigned long long)dw);
    }
    if (kq == 0 && n < 8)
      AS(g_pa0 + (size_t)ocol * 4 + b,
         (1ull << 32) |
             (unsigned long long)__float_as_uint(16.f * hs[ocol]));
  }

  // ---- x prefetch for t=0 ----
  f32x4 xf[16];
  f16x8 xa[8];
  const int arow = 16 * b + n;
  {
    const float* xp = xg + (size_t)arow * S_SEQ * 256 + kq * 8;
#pragma unroll
    for (int kk = 0; kk < 8; ++kk) {
      xf[2 * kk]     = *(const f32x4*)(xp + kk * 32);
      xf[2 * kk + 1] = *(const f32x4*)(xp + kk * 32 + 4);
    }
  }

  for (int t = 0; t < T_TOT; ++t) {
    const float pe0 = (float)(t + 1);
    const float pe1 = (pe0 - 1028.5f) * (1.0f / 1028.5f);
    const int have_x = (t < S_SEQ);

    // ---------------- phase A: o1 = (h1 + calc(h0c, s, W0)) * 0.5 ----------
    {
      f32x4 acc0, acc1;
      const float pt = pe0 * w0pa + pe1 * w0pb;
      acc0[0] = pt; acc0[1] = pt; acc0[2] = pt; acc0[3] = pt;
      acc1[0] = 0.f; acc1[1] = 0.f; acc1[2] = 0.f; acc1[3] = 0.f;
      // x part BEFORE the poll: overlaps the spin / off the critical path.
      if (have_x) {
#pragma unroll
        for (int kk = 0; kk < 8; ++kk) {
          f16x8 af;
#pragma unroll
          for (int j = 0; j < 4; ++j) {
            af[j]     = (_Float16)xf[2 * kk][j];
            af[4 + j] = (_Float16)xf[2 * kk + 1][j];
          }
          xa[kk] = af;
          if (kk & 1)
            acc1 = __builtin_amdgcn_mfma_f32_16x16x32_f16(af, w0x[kk], acc1,
                                                          0, 0, 0);
          else
            acc0 = __builtin_amdgcn_mfma_f32_16x16x32_f16(af, w0x[kk], acc0,
                                                          0, 0, 0);
        }
      }
      PHASE(w0s, g_st0, g_pa0, 2 * t + 1, g_st1, g_pa1, 2 * t + 2, raw1);
    }

    // ---------------- phase B: o0 = (h0 + calc(o1c, s, W1)) * 0.5 ----------
    {
      f32x4 acc0, acc1;
      const float pt = pe0 * w1pa + pe1 * w1pb;
      acc0[0] = pt; acc0[1] = pt; acc0[2] = pt; acc0[3] = pt;
      acc1[0] = 0.f; acc1[1] = 0.f; acc1[2] = 0.f; acc1[3] = 0.f;
      if (have_x) {
#pragma unroll
        for (int kk = 0; kk < 8; ++kk) {
          if (kk & 1)
            acc1 = __builtin_amdgcn_mfma_f32_16x16x32_f16(xa[kk], w1x[kk],
                                                          acc1, 0, 0, 0);
          else
            acc0 = __builtin_amdgcn_mfma_f32_16x16x32_f16(xa[kk], w1x[kk],
                                                          acc0, 0, 0, 0);
        }
      }
      // prefetch x(t+1): in flight across poll B + phase-A conversion.
      if (t + 1 < S_SEQ) {
        const float* xp = xg + ((size_t)arow * S_SEQ + (t + 1)) * 256 + kq * 8;
#pragma unroll
        for (int kk = 0; kk < 8; ++kk) {
          xf[2 * kk]     = *(const f32x4*)(xp + kk * 32);
          xf[2 * kk + 1] = *(const f32x4*)(xp + kk * 32 + 4);
        }
      }
      PHASE(w1s, g_st1, g_pa1, 2 * t + 2, g_st0, g_pa0, 2 * t + 3, raw0);
    }
  }

  // ---- final h = [o0 | o1] fp32 ----
  if (n < 8) {
#pragma unroll
    for (int r = 0; r < 4; ++r) {
      const int row = 16 * b + kq * 4 + r;
      out[(size_t)row * 512 + ocol] = raw0[r];
      out[(size_t)row * 512 + 256 + ocol] = raw1[r];
    }
  }
}

#undef PHASE
#undef AS
#undef AL

extern "C" void kernel_launch(void* const* d_in, const int* in_sizes, int n_in,
                              void* d_out, int out_size, void* d_ws, size_t ws_size,
                              hipStream_t stream) {
  (void)in_sizes; (void)n_in; (void)out_size; (void)d_ws; (void)ws_size;
  const float* x  = (const float*)d_in[0];
  const float* hs = (const float*)d_in[1];
  const float* W0 = (const float*)d_in[2];
  const float* W1 = (const float*)d_in[3];
  float* out = (float*)d_out;

  // prologue kernel zeroes the tagged exchange globals (stream-ordered, so
  // it completes before rnn_kernel; replayed per graph iteration -> tags
  // reset each run). No workspace usage at all.
  init_ws<<<dim3(32), dim3(256), 0, stream>>>();
  rnn_kernel<<<dim3(32), dim3(256), 0, stream>>>(x, hs, W0, W1, out);
}